// Round 1
// baseline (453.257 us; speedup 1.0000x reference)
//
#include <hip/hip_runtime.h>

typedef unsigned short u16;
typedef u16   u16x4 __attribute__((ext_vector_type(4)));
typedef u16   u16x8 __attribute__((ext_vector_type(8)));
typedef short s16x4 __attribute__((ext_vector_type(4)));
typedef __bf16 bf16x8 __attribute__((ext_vector_type(8)));
typedef float f32x4 __attribute__((ext_vector_type(4)));

#define LDP 264   // padded row stride (bf16 elems) for [64][256] tiles
#define VTP 72    // padded row stride for vT [256][64]

__device__ __forceinline__ u16 f2b(float f) {
  union { float f; unsigned u; } c; c.f = f;
  return (u16)((c.u + 0x7fffu + ((c.u >> 16) & 1u)) >> 16);
}
__device__ __forceinline__ float b2f(u16 h) {
  union { unsigned u; float f; } c; c.u = ((unsigned)h) << 16;
  return c.f;
}
__device__ __forceinline__ bf16x8 ld16(const u16* p) {
  return __builtin_bit_cast(bf16x8, *reinterpret_cast<const u16x8*>(p));
}
__device__ __forceinline__ f32x4 z4() { f32x4 z; z[0]=0.f; z[1]=0.f; z[2]=0.f; z[3]=0.f; return z; }

// ---------------- prep: weights->bf16, biasT[h][k][q], maskT[w][k][q] --------
// ws layout (bytes):
//   0        : wq  bf16  768*256          (393216 B)
//   393216   : wp  bf16  256*256          (131072 B)
//   524288   : biasT f32 8*64*64          (131072 B)
//   655360   : maskT f32 256*64*64        (4194304 B)   total 4849664 B
__global__ void prep_kernel(const float* __restrict__ qkv_w, const float* __restrict__ proj_w,
                            const float* __restrict__ mask, const float* __restrict__ table,
                            const int* __restrict__ rpi,
                            u16* __restrict__ wq, u16* __restrict__ wp,
                            float* __restrict__ biasT, float* __restrict__ maskT) {
  int i = blockIdx.x * 512 + threadIdx.x;
  if (i < 196608) { wq[i] = f2b(qkv_w[i]); return; }
  i -= 196608;
  if (i < 65536) { wp[i] = f2b(proj_w[i]); return; }
  i -= 65536;
  if (i < 32768) {  // biasT[h][ktok][qtok] = table[rpi[qtok][ktok]*8 + h]
    int h = i >> 12, a = (i >> 6) & 63, q = i & 63;
    biasT[i] = table[rpi[q * 64 + a] * 8 + h];
    return;
  }
  i -= 32768;
  if (i < 1048576) {  // maskT[w][ktok][qtok] = mask[w][qtok][ktok]
    int w = i >> 12, a = (i >> 6) & 63, q = i & 63;
    maskT[i] = mask[(w << 12) + (q << 6) + a];
  }
}

// ---------------- fused window attention: 1 block (512 thr, 8 waves)/window --
__global__ __launch_bounds__(512, 2) void winattn_kernel(
    const float* __restrict__ x, const float* __restrict__ qkv_b,
    const float* __restrict__ proj_b, const float* __restrict__ logit_scale,
    const u16* __restrict__ wq, const u16* __restrict__ wp,
    const float* __restrict__ biasT, const float* __restrict__ maskT,
    float* __restrict__ out) {
  __shared__ u16 qL[64][LDP];    // 33792 B
  __shared__ u16 kL[64][LDP];    // 33792 B
  __shared__ u16 vT[256][VTP];   // 36864 B  (v transposed: [h*32+d][token])
  __shared__ u16 xb[64][LDP];    // 33792 B  (x bf16; reused as attn-out for proj)

  const int b    = blockIdx.x;
  const int tid  = threadIdx.x;
  const int wave = tid >> 6;
  const int lane = tid & 63;
  const int lr   = lane & 15;   // fragment row/col index
  const int lg   = lane >> 4;   // fragment k-group

  // ---- Phase 0: stage x (fp32 -> bf16) into xb ----
  const float4* xg4 = reinterpret_cast<const float4*>(x + (size_t)b * 16384);
#pragma unroll
  for (int j = 0; j < 8; ++j) {
    int e4 = tid + j * 512;            // float4 index 0..4095
    float4 v = xg4[e4];
    int e = e4 * 4, tok = e >> 8, c = e & 255;
    u16x4 h;
    h[0] = f2b(v.x); h[1] = f2b(v.y); h[2] = f2b(v.z); h[3] = f2b(v.w);
    *reinterpret_cast<u16x4*>(&xb[tok][c]) = h;
  }
  __syncthreads();

  // ---- Phase 1: qkv = xb @ qkv_w^T + b; q->qL, k->kL, v->vT (transposed) ----
  // wave owns output cols [96*wave, 96*wave+96), processed as 2 groups of 3 tiles
#pragma unroll 1
  for (int ng = 0; ng < 2; ++ng) {
    const int nb0 = wave * 96 + ng * 48;
    const u16* wrow0 = wq + (nb0 +  0 + lr) * 256 + lg * 8;
    const u16* wrow1 = wq + (nb0 + 16 + lr) * 256 + lg * 8;
    const u16* wrow2 = wq + (nb0 + 32 + lr) * 256 + lg * 8;
    f32x4 acc[3][4];
#pragma unroll
    for (int j = 0; j < 3; ++j)
#pragma unroll
      for (int mt = 0; mt < 4; ++mt) acc[j][mt] = z4();
#pragma unroll
    for (int ks = 0; ks < 8; ++ks) {
      bf16x8 bf0 = ld16(wrow0 + ks * 32);
      bf16x8 bf1 = ld16(wrow1 + ks * 32);
      bf16x8 bf2 = ld16(wrow2 + ks * 32);
#pragma unroll
      for (int mt = 0; mt < 4; ++mt) {
        bf16x8 af = ld16(&xb[mt * 16 + lr][ks * 32 + lg * 8]);
        acc[0][mt] = __builtin_amdgcn_mfma_f32_16x16x32_bf16(af, bf0, acc[0][mt], 0, 0, 0);
        acc[1][mt] = __builtin_amdgcn_mfma_f32_16x16x32_bf16(af, bf1, acc[1][mt], 0, 0, 0);
        acc[2][mt] = __builtin_amdgcn_mfma_f32_16x16x32_bf16(af, bf2, acc[2][mt], 0, 0, 0);
      }
    }
#pragma unroll
    for (int j = 0; j < 3; ++j) {
      const int nb = nb0 + j * 16;
      const int colg = nb + lr;          // C col = lane&15
      const float bias = qkv_b[colg];
      const int seg = nb >> 8;           // 0=q 1=k 2=v (tile never straddles)
#pragma unroll
      for (int mt = 0; mt < 4; ++mt) {
#pragma unroll
        for (int r = 0; r < 4; ++r) {
          int row = mt * 16 + lg * 4 + r;  // C row = (lane>>4)*4 + reg
          u16 hv = f2b(acc[j][mt][r] + bias);
          if (seg == 0)      qL[row][colg] = hv;
          else if (seg == 1) kL[row][colg - 256] = hv;
          else               vT[colg - 512][row] = hv;
        }
      }
    }
  }
  __syncthreads();

  // ---- Phase 1b: L2-normalize q (x logit scale) and k, per (token, head) ----
#pragma unroll
  for (int t2 = 0; t2 < 2; ++t2) {
    int task = tid + t2 * 512;           // 0..1023 = {q,k} x 64 tok x 8 head
    int qk  = task >> 9;
    int tok = (task >> 3) & 63;
    int h   = task & 7;
    u16* base = qk ? &kL[tok][h * 32] : &qL[tok][h * 32];
    float v[32];
    float ss = 0.f;
#pragma unroll
    for (int j4 = 0; j4 < 4; ++j4) {
      u16x8 u = *reinterpret_cast<u16x8*>(base + j4 * 8);
#pragma unroll
      for (int j = 0; j < 8; ++j) { float f = b2f(u[j]); v[j4 * 8 + j] = f; ss += f * f; }
    }
    float inv = 1.0f / fmaxf(sqrtf(ss), 1e-12f);
    if (!qk) inv *= __expf(fminf(logit_scale[h], 4.6051702f));  // ls, folded into q
#pragma unroll
    for (int j4 = 0; j4 < 4; ++j4) {
      u16x8 u;
#pragma unroll
      for (int j = 0; j < 8; ++j) u[j] = f2b(v[j4 * 8 + j] * inv);
      *reinterpret_cast<u16x8*>(base + j4 * 8) = u;
    }
  }
  __syncthreads();

  // ---- Phase 2: attention, one head per wave. ST = K·Q^T (swapped) ----
  {
    const int h = wave;
    bf16x8 kf[4], qf[4];
#pragma unroll
    for (int t = 0; t < 4; ++t) {
      kf[t] = ld16(&kL[t * 16 + lr][h * 32 + lg * 8]);
      qf[t] = ld16(&qL[t * 16 + lr][h * 32 + lg * 8]);
    }
    f32x4 st[4][4];   // [ktile][qtile]; C: row=ktok, col=qtok
#pragma unroll
    for (int kt = 0; kt < 4; ++kt)
#pragma unroll
      for (int qt = 0; qt < 4; ++qt)
        st[kt][qt] = __builtin_amdgcn_mfma_f32_16x16x32_bf16(kf[kt], qf[qt], z4(), 0, 0, 0);

    const float* bT = biasT + h * 4096;
    const float* mT = maskT + (size_t)(b & 255) * 4096;
#pragma unroll
    for (int kt = 0; kt < 4; ++kt)
#pragma unroll
      for (int qt = 0; qt < 4; ++qt)
#pragma unroll
        for (int r = 0; r < 4; ++r) {
          int ktok = kt * 16 + lg * 4 + r, qtok = qt * 16 + lr;
          st[kt][qt][r] += bT[ktok * 64 + qtok] + mT[ktok * 64 + qtok];
        }

    // softmax over ktok (C-row axis): local 16 values + 2 xor-shuffles
#pragma unroll
    for (int qt = 0; qt < 4; ++qt) {
      float m = -1e30f;
#pragma unroll
      for (int kt = 0; kt < 4; ++kt)
#pragma unroll
        for (int r = 0; r < 4; ++r) m = fmaxf(m, st[kt][qt][r]);
      m = fmaxf(m, __shfl_xor(m, 16));
      m = fmaxf(m, __shfl_xor(m, 32));
      float s = 0.f;
#pragma unroll
      for (int kt = 0; kt < 4; ++kt)
#pragma unroll
        for (int r = 0; r < 4; ++r) {
          float e = __expf(st[kt][qt][r] - m);
          st[kt][qt][r] = e; s += e;
        }
      s += __shfl_xor(s, 16);
      s += __shfl_xor(s, 32);
      float inv = 1.0f / s;
#pragma unroll
      for (int kt = 0; kt < 4; ++kt)
#pragma unroll
        for (int r = 0; r < 4; ++r) st[kt][qt][r] *= inv;
    }

    // PV: P^T C-layout == A-frag layout of mfma_16x16x16bf16_1k. O = P·V.
    f32x4 o[4][2];
#pragma unroll
    for (int qt = 0; qt < 4; ++qt)
#pragma unroll
      for (int dt = 0; dt < 2; ++dt) o[qt][dt] = z4();
#pragma unroll
    for (int kt = 0; kt < 4; ++kt) {
      s16x4 pa[4];
#pragma unroll
      for (int qt = 0; qt < 4; ++qt)
#pragma unroll
        for (int i = 0; i < 4; ++i) pa[qt][i] = (short)f2b(st[kt][qt][i]);
#pragma unroll
      for (int dt = 0; dt < 2; ++dt) {
        s16x4 vf = *reinterpret_cast<const s16x4*>(&vT[h * 32 + dt * 16 + lr][kt * 16 + lg * 4]);
#pragma unroll
        for (int qt = 0; qt < 4; ++qt)
          o[qt][dt] = __builtin_amdgcn_mfma_f32_16x16x16bf16_1k(pa[qt], vf, o[qt][dt], 0, 0, 0);
      }
    }
    // write attn-out (bf16) into xb (x no longer needed)
#pragma unroll
    for (int qt = 0; qt < 4; ++qt)
#pragma unroll
      for (int dt = 0; dt < 2; ++dt)
#pragma unroll
        for (int r = 0; r < 4; ++r) {
          int qtok = qt * 16 + lg * 4 + r;
          xb[qtok][h * 32 + dt * 16 + lr] = f2b(o[qt][dt][r]);
        }
  }
  __syncthreads();

  // ---- Phase 3: out = attn_out @ proj_w^T + proj_b (fp32 store) ----
  {
    const int nb0 = wave * 32;
    const u16* wrow0 = wp + (nb0 +  0 + lr) * 256 + lg * 8;
    const u16* wrow1 = wp + (nb0 + 16 + lr) * 256 + lg * 8;
    f32x4 acc[2][4];
#pragma unroll
    for (int j = 0; j < 2; ++j)
#pragma unroll
      for (int mt = 0; mt < 4; ++mt) acc[j][mt] = z4();
#pragma unroll
    for (int ks = 0; ks < 8; ++ks) {
      bf16x8 bf0 = ld16(wrow0 + ks * 32);
      bf16x8 bf1 = ld16(wrow1 + ks * 32);
#pragma unroll
      for (int mt = 0; mt < 4; ++mt) {
        bf16x8 af = ld16(&xb[mt * 16 + lr][ks * 32 + lg * 8]);
        acc[0][mt] = __builtin_amdgcn_mfma_f32_16x16x32_bf16(af, bf0, acc[0][mt], 0, 0, 0);
        acc[1][mt] = __builtin_amdgcn_mfma_f32_16x16x32_bf16(af, bf1, acc[1][mt], 0, 0, 0);
      }
    }
    float* og = out + (size_t)b * 16384;
#pragma unroll
    for (int j = 0; j < 2; ++j) {
      const int colg = nb0 + j * 16 + lr;
      const float pbv = proj_b[colg];
#pragma unroll
      for (int mt = 0; mt < 4; ++mt)
#pragma unroll
        for (int r = 0; r < 4; ++r) {
          int row = mt * 16 + lg * 4 + r;
          og[row * 256 + colg] = acc[j][mt][r] + pbv;
        }
    }
  }
}

extern "C" void kernel_launch(void* const* d_in, const int* in_sizes, int n_in,
                              void* d_out, int out_size, void* d_ws, size_t ws_size,
                              hipStream_t stream) {
  const float* x    = (const float*)d_in[0];
  const float* mask = (const float*)d_in[1];
  const float* qw   = (const float*)d_in[2];
  const float* qb   = (const float*)d_in[3];
  const float* pw   = (const float*)d_in[4];
  const float* pb   = (const float*)d_in[5];
  const float* ls   = (const float*)d_in[6];
  const float* tab  = (const float*)d_in[7];
  const int*   rpi  = (const int*)d_in[8];

  char* ws = (char*)d_ws;
  u16*   wqb   = (u16*)ws;                    // 768*256 bf16
  u16*   wpb   = (u16*)(ws + 393216);         // 256*256 bf16
  float* biasT = (float*)(ws + 524288);       // 8*64*64 f32
  float* maskT = (float*)(ws + 655360);       // 256*64*64 f32

  prep_kernel<<<2624, 512, 0, stream>>>(qw, pw, mask, tab, rpi, wqb, wpb, biasT, maskT);
  winattn_kernel<<<2048, 512, 0, stream>>>(x, qb, pb, ls, wqb, wpb, biasT, maskT,
                                           (float*)d_out);
}